// Round 1
// baseline (567.906 us; speedup 1.0000x reference)
//
#include <hip/hip_runtime.h>

// Problem constants (fixed by setup_inputs)
constexpr int B_ = 8, C_ = 64, O_ = 64, H_ = 128, W_ = 128;
constexpr int K2_ = 9, OFFC = 18;          // 2*K2
constexpr int NPIX = B_ * H_ * W_;         // 131072

// ---------------------------------------------------------------------------
// K0a: transpose x (B,C,H,W) -> xT (B,H,W,C)   [NHWC for coalesced channel taps]
// ---------------------------------------------------------------------------
__global__ __launch_bounds__(256) void k_transpose(const float* __restrict__ x,
                                                   float* __restrict__ xT) {
    __shared__ float lds[64][65];
    int blk = blockIdx.x;                  // grid = B*H*(W/64) = 2048
    int wt  = blk % (W_ / 64);
    int rem = blk / (W_ / 64);
    int h   = rem % H_;
    int b   = rem / H_;
    int w0  = wt * 64;
    int tx  = threadIdx.x & 63;
    int ty  = threadIdx.x >> 6;            // 0..3

    #pragma unroll
    for (int cc = 0; cc < 16; ++cc) {
        int c = cc * 4 + ty;
        lds[c][tx] = x[(((size_t)b * C_ + c) * H_ + h) * W_ + w0 + tx];
    }
    __syncthreads();
    #pragma unroll
    for (int ww = 0; ww < 16; ++ww) {
        int w = ww * 4 + ty;
        xT[(((size_t)b * H_ + h) * W_ + w0 + w) * C_ + tx] = lds[tx][w];
    }
}

// ---------------------------------------------------------------------------
// K0b: transpose w_def (O,C,3,3) -> wT [c*9+k][oc]
// ---------------------------------------------------------------------------
__global__ void k_wprep(const float* __restrict__ w_def, float* __restrict__ wT) {
    int i = blockIdx.x * 256 + threadIdx.x;           // over 64*64*9 = 36864
    if (i < O_ * C_ * K2_) {
        int oc = i / (C_ * K2_);
        int r  = i % (C_ * K2_);                       // r = c*9+k
        wT[r * O_ + oc] = w_def[i];
    }
}

// ---------------------------------------------------------------------------
// K1: offset conv: offs[b,h,w][18] = conv3x3(x, w_off) + b_off
// thread = one pixel, 18 accumulators; w_off staged in LDS as [k][oc][c]
// ---------------------------------------------------------------------------
__global__ __launch_bounds__(256) void k_offconv(const float* __restrict__ xT,
                                                 const float* __restrict__ w_off,
                                                 const float* __restrict__ b_off,
                                                 float* __restrict__ offs) {
    __shared__ float wO[K2_][OFFC][C_];    // 41.5 KB
    int tid = threadIdx.x;
    for (int i = tid; i < K2_ * OFFC * C_; i += 256) {
        int k  = i / (OFFC * C_);
        int r  = i % (OFFC * C_);
        int oc = r / C_;
        int c  = r % C_;
        wO[k][oc][c] = w_off[((size_t)oc * C_ + c) * K2_ + k];
    }
    __syncthreads();

    int p = blockIdx.x * 256 + tid;        // pixel id
    int w   = p % W_;
    int rem = p / W_;
    int h   = rem % H_;
    int b   = rem / H_;

    float acc[OFFC];
    #pragma unroll
    for (int i = 0; i < OFFC; ++i) acc[i] = 0.f;

    for (int k = 0; k < K2_; ++k) {
        int ky = k / 3, kx = k % 3;
        int y = h + ky - 1, x = w + kx - 1;
        if (y < 0 || y >= H_ || x < 0 || x >= W_) continue;
        const float* src = xT + ((size_t)(b * H_ + y) * W_ + x) * C_;
        #pragma unroll 4
        for (int c4 = 0; c4 < C_ / 4; ++c4) {
            float4 xv = *reinterpret_cast<const float4*>(src + c4 * 4);
            #pragma unroll
            for (int oc = 0; oc < OFFC; ++oc) {
                float4 wv = *reinterpret_cast<const float4*>(&wO[k][oc][c4 * 4]);
                acc[oc] += xv.x * wv.x + xv.y * wv.y + xv.z * wv.z + xv.w * wv.w;
            }
        }
    }
    float* dst = offs + (size_t)p * OFFC;
    #pragma unroll
    for (int oc = 0; oc < OFFC; ++oc) dst[oc] = acc[oc] + b_off[oc];
}

// ---------------------------------------------------------------------------
// K2: deformable conv.
// thread = one pixel, acc[64] output channels in VGPRs.
// Weights chunk-staged in LDS (16 channels x 9 taps x 64 oc = 36 KB),
// read as same-address float4 broadcasts (conflict-free).
// ---------------------------------------------------------------------------
__global__ __launch_bounds__(256) void k_deform(const float* __restrict__ xT,
                                                const float* __restrict__ offs,
                                                const float* __restrict__ wT,
                                                const float* __restrict__ b_def,
                                                float* __restrict__ out) {
    __shared__ float wL[16 * K2_][O_];     // 36 KB per chunk
    int tid = threadIdx.x;
    int p   = blockIdx.x * 256 + tid;
    int w   = p % W_;
    int rem = p / W_;
    int h   = rem % H_;
    int b   = rem / H_;

    float acc[O_];
    #pragma unroll
    for (int i = 0; i < O_; ++i) acc[i] = 0.f;

    const float* myoff = offs + (size_t)p * OFFC;

    for (int chunk = 0; chunk < 4; ++chunk) {
        int c0 = chunk * 16;
        __syncthreads();
        // stage 144 rows x 64 oc of wT for channels [c0, c0+16)
        {
            const float4* src4 = reinterpret_cast<const float4*>(wT + (size_t)c0 * K2_ * O_);
            float4* dst4 = reinterpret_cast<float4*>(&wL[0][0]);
            for (int i = tid; i < 144 * O_ / 4; i += 256) dst4[i] = src4[i];
        }
        __syncthreads();

        for (int k = 0; k < K2_; ++k) {
            float dy = myoff[2 * k], dx = myoff[2 * k + 1];
            int ky = k / 3, kx = k % 3;
            float py = (float)(h - 1 + ky) + dy;
            float px = (float)(w - 1 + kx) + dx;
            float y0f = floorf(py), x0f = floorf(px);
            float wy = py - y0f, wx = px - x0f;
            int y0 = (int)y0f, x0 = (int)x0f;
            int y1 = y0 + 1, x1 = x0 + 1;
            float w00 = (1.f - wy) * (1.f - wx);
            float w01 = (1.f - wy) * wx;
            float w10 = wy * (1.f - wx);
            float w11 = wy * wx;
            bool vy0 = (y0 >= 0) & (y0 < H_);
            bool vy1 = (y1 >= 0) & (y1 < H_);
            bool vx0 = (x0 >= 0) & (x0 < W_);
            bool vx1 = (x1 >= 0) & (x1 < W_);
            float m00 = (vy0 && vx0) ? w00 : 0.f;
            float m01 = (vy0 && vx1) ? w01 : 0.f;
            float m10 = (vy1 && vx0) ? w10 : 0.f;
            float m11 = (vy1 && vx1) ? w11 : 0.f;
            int y0c = min(max(y0, 0), H_ - 1), y1c = min(max(y1, 0), H_ - 1);
            int x0c = min(max(x0, 0), W_ - 1), x1c = min(max(x1, 0), W_ - 1);
            const float* p00 = xT + ((size_t)(b * H_ + y0c) * W_ + x0c) * C_;
            const float* p01 = xT + ((size_t)(b * H_ + y0c) * W_ + x1c) * C_;
            const float* p10 = xT + ((size_t)(b * H_ + y1c) * W_ + x0c) * C_;
            const float* p11 = xT + ((size_t)(b * H_ + y1c) * W_ + x1c) * C_;

            #pragma unroll
            for (int c4 = 0; c4 < 4; ++c4) {   // 4 channel-quads within the 16-ch chunk
                int c = c0 + c4 * 4;
                float4 a = *reinterpret_cast<const float4*>(p00 + c);
                float4 bb = *reinterpret_cast<const float4*>(p01 + c);
                float4 cv = *reinterpret_cast<const float4*>(p10 + c);
                float4 d = *reinterpret_cast<const float4*>(p11 + c);
                float s[4];
                s[0] = a.x * m00 + bb.x * m01 + cv.x * m10 + d.x * m11;
                s[1] = a.y * m00 + bb.y * m01 + cv.y * m10 + d.y * m11;
                s[2] = a.z * m00 + bb.z * m01 + cv.z * m10 + d.z * m11;
                s[3] = a.w * m00 + bb.w * m01 + cv.w * m10 + d.w * m11;
                #pragma unroll
                for (int j = 0; j < 4; ++j) {
                    const float* wr = &wL[(c4 * 4 + j) * K2_ + k][0];
                    float sj = s[j];
                    #pragma unroll
                    for (int oc4 = 0; oc4 < 16; ++oc4) {
                        float4 wv = *reinterpret_cast<const float4*>(wr + oc4 * 4);
                        acc[oc4 * 4 + 0] += sj * wv.x;
                        acc[oc4 * 4 + 1] += sj * wv.y;
                        acc[oc4 * 4 + 2] += sj * wv.z;
                        acc[oc4 * 4 + 3] += sj * wv.w;
                    }
                }
            }
        }
    }

    // epilogue: out is (B, O, H, W); each store instr is coalesced across lanes (w fastest)
    #pragma unroll
    for (int oc = 0; oc < O_; ++oc) {
        out[(((size_t)b * O_ + oc) * H_ + h) * W_ + w] = acc[oc] + b_def[oc];
    }
}

// ---------------------------------------------------------------------------
extern "C" void kernel_launch(void* const* d_in, const int* in_sizes, int n_in,
                              void* d_out, int out_size, void* d_ws, size_t ws_size,
                              hipStream_t stream) {
    const float* x     = (const float*)d_in[0];
    const float* w_off = (const float*)d_in[1];
    const float* b_off = (const float*)d_in[2];
    const float* w_def = (const float*)d_in[3];
    const float* b_def = (const float*)d_in[4];
    float* out = (float*)d_out;

    char* ws = (char*)d_ws;
    float* xT   = (float*)ws;                                    // 33,554,432 B
    float* offs = (float*)(ws + 33554432);                       //  9,437,184 B
    float* wT   = (float*)(ws + 33554432 + 9437184);             //    147,456 B
    // total ws use: ~41.2 MB

    k_transpose<<<B_ * H_ * (W_ / 64), 256, 0, stream>>>(x, xT);
    k_wprep<<<(O_ * C_ * K2_ + 255) / 256, 256, 0, stream>>>(w_def, wT);
    k_offconv<<<NPIX / 256, 256, 0, stream>>>(xT, w_off, b_off, offs);
    k_deform<<<NPIX / 256, 256, 0, stream>>>(xT, offs, wT, b_def, out);
}

// Round 2
// 177.700 us; speedup vs baseline: 3.1959x; 3.1959x over previous
//
#include <hip/hip_runtime.h>

// Problem constants (fixed by setup_inputs)
constexpr int B_ = 8, C_ = 64, O_ = 64, H_ = 128, W_ = 128;
constexpr int K2_ = 9, OFFC = 18;          // 2*K2
constexpr int NPIX = B_ * H_ * W_;         // 131072

typedef __attribute__((ext_vector_type(8))) short bf16x8;
typedef __attribute__((ext_vector_type(4))) float f32x4;

__device__ __forceinline__ unsigned short f2bf(float f) {
    unsigned int u = __float_as_uint(f);
    u += 0x7fffu + ((u >> 16) & 1u);       // round-to-nearest-even
    return (unsigned short)(u >> 16);
}

// ---------------------------------------------------------------------------
// K0a: transpose x (B,C,H,W) -> xT (B,H,W,C)
// ---------------------------------------------------------------------------
__global__ __launch_bounds__(256) void k_transpose(const float* __restrict__ x,
                                                   float* __restrict__ xT) {
    __shared__ float lds[64][65];
    int blk = blockIdx.x;                  // grid = B*H*(W/64) = 2048
    int wt  = blk % (W_ / 64);
    int rem = blk / (W_ / 64);
    int h   = rem % H_;
    int b   = rem / H_;
    int w0  = wt * 64;
    int tx  = threadIdx.x & 63;
    int ty  = threadIdx.x >> 6;            // 0..3

    #pragma unroll
    for (int cc = 0; cc < 16; ++cc) {
        int c = cc * 4 + ty;
        lds[c][tx] = x[(((size_t)b * C_ + c) * H_ + h) * W_ + w0 + tx];
    }
    __syncthreads();
    #pragma unroll
    for (int ww = 0; ww < 16; ++ww) {
        int w = ww * 4 + ty;
        xT[(((size_t)b * H_ + h) * W_ + w0 + w) * C_ + tx] = lds[tx][w];
    }
}

// ---------------------------------------------------------------------------
// K0b: w_def (O,C,3,3) -> wTfrag, bf16 in MFMA B-fragment order.
// frag f = kc*4 + nt  (kc = K-chunk of 32, nt = 16-oc tile); lane l, elem j:
//   oc = nt*16 + (l&15);  K = kc*32 + (l>>4)*8 + j;  K = tap*64 + c
// ---------------------------------------------------------------------------
__global__ void k_wprep(const float* __restrict__ w_def,
                        unsigned short* __restrict__ wTfrag) {
    int i = blockIdx.x * 256 + threadIdx.x;           // over 72*512 = 36864
    if (i >= O_ * C_ * K2_) return;
    int f = i >> 9;            // /512
    int l = (i >> 3) & 63;
    int j = i & 7;
    int kc = f >> 2, nt = f & 3;
    int oc = nt * 16 + (l & 15);
    int K  = kc * 32 + ((l >> 4) << 3) + j;
    int tap = K >> 6, c = K & 63;
    wTfrag[i] = f2bf(w_def[(size_t)oc * (C_ * K2_) + c * K2_ + tap]);
}

// ---------------------------------------------------------------------------
// K1: offset conv (unchanged except chunked-XCD block swizzle)
// ---------------------------------------------------------------------------
__global__ __launch_bounds__(256) void k_offconv(const float* __restrict__ xT,
                                                 const float* __restrict__ w_off,
                                                 const float* __restrict__ b_off,
                                                 float* __restrict__ offs) {
    __shared__ float wO[K2_][OFFC][C_];    // 41.5 KB
    int tid = threadIdx.x;
    for (int i = tid; i < K2_ * OFFC * C_; i += 256) {
        int k  = i / (OFFC * C_);
        int r  = i % (OFFC * C_);
        int oc = r / C_;
        int c  = r % C_;
        wO[k][oc][c] = w_off[((size_t)oc * C_ + c) * K2_ + k];
    }
    __syncthreads();

    int bid = blockIdx.x;                  // 512 blocks; chunked XCD swizzle
    int swz = (bid & 7) * 64 + (bid >> 3);
    int p = swz * 256 + tid;
    int w   = p % W_;
    int rem = p / W_;
    int h   = rem % H_;
    int b   = rem / H_;

    float acc[OFFC];
    #pragma unroll
    for (int i = 0; i < OFFC; ++i) acc[i] = 0.f;

    for (int k = 0; k < K2_; ++k) {
        int ky = k / 3, kx = k % 3;
        int y = h + ky - 1, x = w + kx - 1;
        if (y < 0 || y >= H_ || x < 0 || x >= W_) continue;
        const float* src = xT + ((size_t)(b * H_ + y) * W_ + x) * C_;
        #pragma unroll 4
        for (int c4 = 0; c4 < C_ / 4; ++c4) {
            float4 xv = *reinterpret_cast<const float4*>(src + c4 * 4);
            #pragma unroll
            for (int oc = 0; oc < OFFC; ++oc) {
                float4 wv = *reinterpret_cast<const float4*>(&wO[k][oc][c4 * 4]);
                acc[oc] += xv.x * wv.x + xv.y * wv.y + xv.z * wv.z + xv.w * wv.w;
            }
        }
    }
    float* dst = offs + (size_t)p * OFFC;
    #pragma unroll
    for (int oc = 0; oc < OFFC; ++oc) dst[oc] = acc[oc] + b_off[oc];
}

// ---------------------------------------------------------------------------
// K2: fused bilinear-sample (global->LDS bf16) + MFMA GEMM + coalesced store.
// Block = 64 pixels, 256 threads (4 waves). LDS: sampled [64 px][576 K] bf16,
// XOR-swizzled (byte ^ (px&7)<<4). Wave w computes 64px x 16oc (nt = w).
// ---------------------------------------------------------------------------
__global__ __launch_bounds__(256) void k_fused(const float* __restrict__ xT,
                                               const float* __restrict__ offs,
                                               const unsigned short* __restrict__ wTfrag,
                                               const float* __restrict__ b_def,
                                               float* __restrict__ out) {
    __shared__ __align__(16) char smem[64 * 1152];   // 72 KB

    // chunked XCD swizzle: each XCD gets 256 contiguous blocks (= one image)
    int bid = blockIdx.x;                  // grid = 2048
    int swz = (bid & 7) * 256 + (bid >> 3);
    int px0 = swz * 64;
    int b  = px0 >> 14;                    // / (H*W)
    int h  = (px0 >> 7) & (H_ - 1);
    int w0 = px0 & (W_ - 1);               // 0 or 64

    int tid  = threadIdx.x;
    int lane = tid & 63;
    int wave = tid >> 6;

    // --- B-fragment preload (latency hidden under sampling) ---
    bf16x8 Bf[18];
    #pragma unroll
    for (int kc = 0; kc < 18; ++kc) {
        Bf[kc] = *reinterpret_cast<const bf16x8*>(
            wTfrag + (((kc * 4 + wave) * 64 + lane) << 3));
    }

    // --- sampling phase: thread = (pixel, 16-ch quarter) ---
    {
        int pxl = tid >> 2;                // 0..63
        int q   = tid & 3;
        int c0  = q * 16;
        int wg  = w0 + pxl;
        const float* myoff = offs + (size_t)(px0 + pxl) * OFFC;
        char* rowbase = smem + pxl * 1152;
        unsigned rs = (unsigned)((pxl & 7) << 4);

        #pragma unroll 3
        for (int ky = 0; ky < 3; ++ky) {
            #pragma unroll 3
            for (int kx = 0; kx < 3; ++kx) {
                int k = ky * 3 + kx;
                float2 dv = *reinterpret_cast<const float2*>(myoff + 2 * k);
                float py  = (float)(h - 1 + ky) + dv.x;
                float pxf = (float)(wg - 1 + kx) + dv.y;
                float y0f = floorf(py), x0f = floorf(pxf);
                float wy = py - y0f, wx = pxf - x0f;
                int y0 = (int)y0f, x0 = (int)x0f;
                int y1 = y0 + 1, x1 = x0 + 1;
                bool vy0 = (y0 >= 0) & (y0 < H_);
                bool vy1 = (y1 >= 0) & (y1 < H_);
                bool vx0 = (x0 >= 0) & (x0 < W_);
                bool vx1 = (x1 >= 0) & (x1 < W_);
                float m00 = (vy0 && vx0) ? (1.f - wy) * (1.f - wx) : 0.f;
                float m01 = (vy0 && vx1) ? (1.f - wy) * wx : 0.f;
                float m10 = (vy1 && vx0) ? wy * (1.f - wx) : 0.f;
                float m11 = (vy1 && vx1) ? wy * wx : 0.f;
                int y0c = min(max(y0, 0), H_ - 1), y1c = min(max(y1, 0), H_ - 1);
                int x0c = min(max(x0, 0), W_ - 1), x1c = min(max(x1, 0), W_ - 1);
                const float* p00 = xT + (((size_t)(b * H_ + y0c)) * W_ + x0c) * C_ + c0;
                const float* p01 = xT + (((size_t)(b * H_ + y0c)) * W_ + x1c) * C_ + c0;
                const float* p10 = xT + (((size_t)(b * H_ + y1c)) * W_ + x0c) * C_ + c0;
                const float* p11 = xT + (((size_t)(b * H_ + y1c)) * W_ + x1c) * C_ + c0;

                float s[16];
                #pragma unroll
                for (int c4 = 0; c4 < 4; ++c4) {
                    float4 a  = *reinterpret_cast<const float4*>(p00 + c4 * 4);
                    float4 bb = *reinterpret_cast<const float4*>(p01 + c4 * 4);
                    float4 cv = *reinterpret_cast<const float4*>(p10 + c4 * 4);
                    float4 d  = *reinterpret_cast<const float4*>(p11 + c4 * 4);
                    s[c4 * 4 + 0] = a.x * m00 + bb.x * m01 + cv.x * m10 + d.x * m11;
                    s[c4 * 4 + 1] = a.y * m00 + bb.y * m01 + cv.y * m10 + d.y * m11;
                    s[c4 * 4 + 2] = a.z * m00 + bb.z * m01 + cv.z * m10 + d.z * m11;
                    s[c4 * 4 + 3] = a.w * m00 + bb.w * m01 + cv.w * m10 + d.w * m11;
                }
                bf16x8 v0, v1;
                #pragma unroll
                for (int j = 0; j < 8; ++j) {
                    v0[j] = (short)f2bf(s[j]);
                    v1[j] = (short)f2bf(s[8 + j]);
                }
                unsigned ib = (unsigned)(k * 128 + q * 32);   // K = k*64 + c0
                *reinterpret_cast<bf16x8*>(rowbase + (ib ^ rs)) = v0;
                *reinterpret_cast<bf16x8*>(rowbase + ((ib + 16) ^ rs)) = v1;
            }
        }
    }
    __syncthreads();

    // --- MFMA phase: wave w -> oc tile [w*16, w*16+16), all 64 px ---
    f32x4 acc[4];
    #pragma unroll
    for (int m = 0; m < 4; ++m) acc[m] = (f32x4){0.f, 0.f, 0.f, 0.f};

    int colbase = (lane >> 4) << 4;        // byte offset of this lane's 8 K-elems
    #pragma unroll
    for (int m = 0; m < 4; ++m) {
        int row = m * 16 + (lane & 15);
        const char* rbase = smem + row * 1152;
        unsigned rsw = (unsigned)((row & 7) << 4);
        #pragma unroll
        for (int kc = 0; kc < 18; ++kc) {
            bf16x8 a = *reinterpret_cast<const bf16x8*>(
                rbase + (((unsigned)(kc * 64 + colbase)) ^ rsw));
            acc[m] = __builtin_amdgcn_mfma_f32_16x16x32_bf16(a, Bf[kc], acc[m], 0, 0, 0);
        }
    }
    __syncthreads();

    // --- epilogue: stage 64px x 64oc f32 tile, coalesced NCHW store ---
    float* ot = reinterpret_cast<float*>(smem);          // [64][65]
    float bias = b_def[wave * 16 + (lane & 15)];
    #pragma unroll
    for (int m = 0; m < 4; ++m) {
        #pragma unroll
        for (int j = 0; j < 4; ++j) {
            int prow = m * 16 + ((lane >> 4) << 2) + j;   // pixel
            ot[prow * 65 + wave * 16 + (lane & 15)] = acc[m][j] + bias;
        }
    }
    __syncthreads();
    #pragma unroll
    for (int r = 0; r < 16; ++r) {
        int idx = r * 256 + tid;
        int oc = idx >> 6, pw = idx & 63;
        out[(((size_t)b * O_ + oc) * H_ + h) * W_ + w0 + pw] = ot[pw * 65 + oc];
    }
}

// ---------------------------------------------------------------------------
extern "C" void kernel_launch(void* const* d_in, const int* in_sizes, int n_in,
                              void* d_out, int out_size, void* d_ws, size_t ws_size,
                              hipStream_t stream) {
    const float* x     = (const float*)d_in[0];
    const float* w_off = (const float*)d_in[1];
    const float* b_off = (const float*)d_in[2];
    const float* w_def = (const float*)d_in[3];
    const float* b_def = (const float*)d_in[4];
    float* out = (float*)d_out;

    char* ws = (char*)d_ws;
    float* xT             = (float*)ws;                              // 33,554,432 B
    float* offs           = (float*)(ws + 33554432);                 //  9,437,184 B
    unsigned short* wTf   = (unsigned short*)(ws + 33554432 + 9437184); //  73,728 B

    k_transpose<<<B_ * H_ * (W_ / 64), 256, 0, stream>>>(x, xT);
    k_wprep<<<(O_ * C_ * K2_ + 255) / 256, 256, 0, stream>>>(w_def, wTf);
    k_offconv<<<NPIX / 256, 256, 0, stream>>>(xT, w_off, b_off, offs);
    k_fused<<<NPIX / 64, 256, 0, stream>>>(xT, offs, wTf, b_def, out);
}

// Round 3
// 124.478 us; speedup vs baseline: 4.5623x; 1.4276x over previous
//
#include <hip/hip_runtime.h>

// Problem constants (fixed by setup_inputs)
constexpr int B_ = 8, C_ = 64, O_ = 64, H_ = 128, W_ = 128;
constexpr int K2_ = 9, OFFC = 18;          // 2*K2
constexpr int NPIX = B_ * H_ * W_;         // 131072

typedef __attribute__((ext_vector_type(8))) short bf16x8;
typedef __attribute__((ext_vector_type(4))) float f32x4;

__device__ __forceinline__ unsigned short f2bf(float f) {
    unsigned int u = __float_as_uint(f);
    u += 0x7fffu + ((u >> 16) & 1u);       // round-to-nearest-even
    return (unsigned short)(u >> 16);
}

// ---------------------------------------------------------------------------
// K0a: transpose x (B,C,H,W) -> xT (B,H,W,C)
// ---------------------------------------------------------------------------
__global__ __launch_bounds__(256) void k_transpose(const float* __restrict__ x,
                                                   float* __restrict__ xT) {
    __shared__ float lds[64][65];
    int blk = blockIdx.x;                  // grid = B*H*(W/64) = 2048
    int wt  = blk % (W_ / 64);
    int rem = blk / (W_ / 64);
    int h   = rem % H_;
    int b   = rem / H_;
    int w0  = wt * 64;
    int tx  = threadIdx.x & 63;
    int ty  = threadIdx.x >> 6;            // 0..3

    #pragma unroll
    for (int cc = 0; cc < 16; ++cc) {
        int c = cc * 4 + ty;
        lds[c][tx] = x[(((size_t)b * C_ + c) * H_ + h) * W_ + w0 + tx];
    }
    __syncthreads();
    #pragma unroll
    for (int ww = 0; ww < 16; ++ww) {
        int w = ww * 4 + ty;
        xT[(((size_t)b * H_ + h) * W_ + w0 + w) * C_ + tx] = lds[tx][w];
    }
}

// ---------------------------------------------------------------------------
// K0b: w_def (O,C,3,3) -> wTfrag, bf16 in MFMA B-fragment order.
// frag f = kc*4 + nt; lane l, elem j: oc = nt*16+(l&15); K = kc*32+(l>>4)*8+j
// K = tap*64 + c
// ---------------------------------------------------------------------------
__global__ void k_wprep(const float* __restrict__ w_def,
                        unsigned short* __restrict__ wTfrag) {
    int i = blockIdx.x * 256 + threadIdx.x;           // over 72*512 = 36864
    if (i >= O_ * C_ * K2_) return;
    int f = i >> 9;            // /512
    int l = (i >> 3) & 63;
    int j = i & 7;
    int kc = f >> 2, nt = f & 3;
    int oc = nt * 16 + (l & 15);
    int K  = kc * 32 + ((l >> 4) << 3) + j;
    int tap = K >> 6, c = K & 63;
    wTfrag[i] = f2bf(w_def[(size_t)oc * (C_ * K2_) + c * K2_ + tap]);
}

// ---------------------------------------------------------------------------
// K0c: w_off (18,C,3,3) -> wOfrag, bf16 B-fragment order, N padded 18->32.
// frag f = kc*2 + nt (kc in [0,18), nt in [0,2)); oc = nt*16+(l&15) (0 if >=18)
// ---------------------------------------------------------------------------
__global__ void k_wprep_off(const float* __restrict__ w_off,
                            unsigned short* __restrict__ wOfrag) {
    int i = blockIdx.x * 256 + threadIdx.x;           // over 36*512 = 18432
    if (i >= 36 * 512) return;
    int f = i >> 9;
    int l = (i >> 3) & 63;
    int j = i & 7;
    int kc = f >> 1, nt = f & 1;
    int oc = nt * 16 + (l & 15);
    int K  = kc * 32 + ((l >> 4) << 3) + j;
    int tap = K >> 6, c = K & 63;
    float v = (oc < OFFC) ? w_off[((size_t)oc * C_ + c) * K2_ + tap] : 0.f;
    wOfrag[i] = f2bf(v);
}

// ---------------------------------------------------------------------------
// K1: fully fused: im2col tile -> offset MFMA GEMM -> bilinear sample tile ->
//     main MFMA GEMM -> coalesced NCHW store.
// Block = 64 pixels (one row segment), 256 threads (4 waves).
// LDS: tile [64 px][576 K] bf16, XOR-swizzled (byte ^ (px&7)<<4)  = 72 KB
//      offsBuf [64][20] f32                                       =  5 KB
// ---------------------------------------------------------------------------
__global__ __launch_bounds__(256) void k_fused(const float* __restrict__ xT,
                                               const unsigned short* __restrict__ wOfrag,
                                               const float* __restrict__ b_off,
                                               const unsigned short* __restrict__ wTfrag,
                                               const float* __restrict__ b_def,
                                               float* __restrict__ out) {
    __shared__ __align__(16) char smem[64 * 1152];   // 72 KB
    __shared__ float offsBuf[64][20];                // 5 KB

    // chunked XCD swizzle: each XCD gets 256 contiguous blocks (= one image)
    int bid = blockIdx.x;                  // grid = 2048
    int swz = (bid & 7) * 256 + (bid >> 3);
    int px0 = swz * 64;
    int b  = px0 >> 14;                    // / (H*W)
    int h  = (px0 >> 7) & (H_ - 1);
    int w0 = px0 & (W_ - 1);               // 0 or 64

    int tid  = threadIdx.x;
    int lane = tid & 63;
    int wave = tid >> 6;

    // --- main-GEMM B-fragment preload (latency hidden under im2col) ---
    bf16x8 Bf[18];
    #pragma unroll
    for (int kc = 0; kc < 18; ++kc) {
        Bf[kc] = *reinterpret_cast<const bf16x8*>(
            wTfrag + (((kc * 4 + wave) * 64 + lane) << 3));
    }

    int pxl = tid >> 2;                    // 0..63 (wave-local rows: pxl in [wave*16, wave*16+16))
    int q   = tid & 3;
    int c0  = q * 16;
    int wg  = w0 + pxl;
    char* rowbase = smem + pxl * 1152;
    unsigned rs = (unsigned)((pxl & 7) << 4);

    // --- phase 1: im2col tile (integer taps, zero-padded) ---
    #pragma unroll 3
    for (int ky = 0; ky < 3; ++ky) {
        int y = h - 1 + ky;
        bool vy = (y >= 0) & (y < H_);
        #pragma unroll 3
        for (int kx = 0; kx < 3; ++kx) {
            int k = ky * 3 + kx;
            int x = wg - 1 + kx;
            bool v = vy & (x >= 0) & (x < W_);
            bf16x8 v0, v1;
            if (v) {
                const float* src = xT + (((size_t)(b * H_ + y)) * W_ + x) * C_ + c0;
                #pragma unroll
                for (int c4 = 0; c4 < 2; ++c4) {
                    float4 f0 = *reinterpret_cast<const float4*>(src + c4 * 8);
                    float4 f1 = *reinterpret_cast<const float4*>(src + c4 * 8 + 4);
                    bf16x8& dst = c4 ? v1 : v0;
                    dst[0] = (short)f2bf(f0.x); dst[1] = (short)f2bf(f0.y);
                    dst[2] = (short)f2bf(f0.z); dst[3] = (short)f2bf(f0.w);
                    dst[4] = (short)f2bf(f1.x); dst[5] = (short)f2bf(f1.y);
                    dst[6] = (short)f2bf(f1.z); dst[7] = (short)f2bf(f1.w);
                }
            } else {
                v0 = (bf16x8){0,0,0,0,0,0,0,0};
                v1 = (bf16x8){0,0,0,0,0,0,0,0};
            }
            unsigned ib = (unsigned)(k * 128 + q * 32);   // K = k*64 + c0
            *reinterpret_cast<bf16x8*>(rowbase + (ib ^ rs)) = v0;
            *reinterpret_cast<bf16x8*>(rowbase + ((ib + 16) ^ rs)) = v1;
        }
    }
    __syncthreads();

    // --- phase 2: offset GEMM. wave w -> its own 16-px M-tile, 32 (18) oc ---
    {
        f32x4 acc2[2];
        acc2[0] = (f32x4){0.f, 0.f, 0.f, 0.f};
        acc2[1] = (f32x4){0.f, 0.f, 0.f, 0.f};
        int colbase = (lane >> 4) << 4;
        int rowA = wave * 16 + (lane & 15);
        const char* rbaseA = smem + rowA * 1152;
        unsigned rswA = (unsigned)((rowA & 7) << 4);
        #pragma unroll
        for (int kc = 0; kc < 18; ++kc) {
            bf16x8 a = *reinterpret_cast<const bf16x8*>(
                rbaseA + (((unsigned)(kc * 64 + colbase)) ^ rswA));
            bf16x8 b0 = *reinterpret_cast<const bf16x8*>(wOfrag + (((kc * 2 + 0) * 64 + lane) << 3));
            bf16x8 b1 = *reinterpret_cast<const bf16x8*>(wOfrag + (((kc * 2 + 1) * 64 + lane) << 3));
            acc2[0] = __builtin_amdgcn_mfma_f32_16x16x32_bf16(a, b0, acc2[0], 0, 0, 0);
            acc2[1] = __builtin_amdgcn_mfma_f32_16x16x32_bf16(a, b1, acc2[1], 0, 0, 0);
        }
        #pragma unroll
        for (int nt = 0; nt < 2; ++nt) {
            int oc = nt * 16 + (lane & 15);
            if (oc < OFFC) {
                float bo = b_off[oc];
                #pragma unroll
                for (int j = 0; j < 4; ++j) {
                    int px = wave * 16 + ((lane >> 4) << 2) + j;
                    offsBuf[px][oc] = acc2[nt][j] + bo;
                }
            }
        }
    }
    __syncthreads();

    // --- phase 3: bilinear sampling, overwrite tile ---
    {
        #pragma unroll 3
        for (int ky = 0; ky < 3; ++ky) {
            #pragma unroll 3
            for (int kx = 0; kx < 3; ++kx) {
                int k = ky * 3 + kx;
                float2 dv = *reinterpret_cast<const float2*>(&offsBuf[pxl][2 * k]);
                float py  = (float)(h - 1 + ky) + dv.x;
                float pxf = (float)(wg - 1 + kx) + dv.y;
                float y0f = floorf(py), x0f = floorf(pxf);
                float wy = py - y0f, wx = pxf - x0f;
                int y0 = (int)y0f, x0 = (int)x0f;
                int y1 = y0 + 1, x1 = x0 + 1;
                bool vy0 = (y0 >= 0) & (y0 < H_);
                bool vy1 = (y1 >= 0) & (y1 < H_);
                bool vx0 = (x0 >= 0) & (x0 < W_);
                bool vx1 = (x1 >= 0) & (x1 < W_);
                float m00 = (vy0 && vx0) ? (1.f - wy) * (1.f - wx) : 0.f;
                float m01 = (vy0 && vx1) ? (1.f - wy) * wx : 0.f;
                float m10 = (vy1 && vx0) ? wy * (1.f - wx) : 0.f;
                float m11 = (vy1 && vx1) ? wy * wx : 0.f;
                int y0c = min(max(y0, 0), H_ - 1), y1c = min(max(y1, 0), H_ - 1);
                int x0c = min(max(x0, 0), W_ - 1), x1c = min(max(x1, 0), W_ - 1);
                const float* p00 = xT + (((size_t)(b * H_ + y0c)) * W_ + x0c) * C_ + c0;
                const float* p01 = xT + (((size_t)(b * H_ + y0c)) * W_ + x1c) * C_ + c0;
                const float* p10 = xT + (((size_t)(b * H_ + y1c)) * W_ + x0c) * C_ + c0;
                const float* p11 = xT + (((size_t)(b * H_ + y1c)) * W_ + x1c) * C_ + c0;

                float s[16];
                #pragma unroll
                for (int c4 = 0; c4 < 4; ++c4) {
                    float4 a  = *reinterpret_cast<const float4*>(p00 + c4 * 4);
                    float4 bb = *reinterpret_cast<const float4*>(p01 + c4 * 4);
                    float4 cv = *reinterpret_cast<const float4*>(p10 + c4 * 4);
                    float4 d  = *reinterpret_cast<const float4*>(p11 + c4 * 4);
                    s[c4 * 4 + 0] = a.x * m00 + bb.x * m01 + cv.x * m10 + d.x * m11;
                    s[c4 * 4 + 1] = a.y * m00 + bb.y * m01 + cv.y * m10 + d.y * m11;
                    s[c4 * 4 + 2] = a.z * m00 + bb.z * m01 + cv.z * m10 + d.z * m11;
                    s[c4 * 4 + 3] = a.w * m00 + bb.w * m01 + cv.w * m10 + d.w * m11;
                }
                bf16x8 v0, v1;
                #pragma unroll
                for (int j = 0; j < 8; ++j) {
                    v0[j] = (short)f2bf(s[j]);
                    v1[j] = (short)f2bf(s[8 + j]);
                }
                unsigned ib = (unsigned)(k * 128 + q * 32);
                *reinterpret_cast<bf16x8*>(rowbase + (ib ^ rs)) = v0;
                *reinterpret_cast<bf16x8*>(rowbase + ((ib + 16) ^ rs)) = v1;
            }
        }
    }
    __syncthreads();

    // --- phase 4: main GEMM: wave w -> oc tile [w*16, w*16+16), all 64 px ---
    f32x4 acc[4];
    #pragma unroll
    for (int m = 0; m < 4; ++m) acc[m] = (f32x4){0.f, 0.f, 0.f, 0.f};

    int colbase = (lane >> 4) << 4;
    #pragma unroll
    for (int m = 0; m < 4; ++m) {
        int row = m * 16 + (lane & 15);
        const char* rbase = smem + row * 1152;
        unsigned rsw = (unsigned)((row & 7) << 4);
        #pragma unroll
        for (int kc = 0; kc < 18; ++kc) {
            bf16x8 a = *reinterpret_cast<const bf16x8*>(
                rbase + (((unsigned)(kc * 64 + colbase)) ^ rsw));
            acc[m] = __builtin_amdgcn_mfma_f32_16x16x32_bf16(a, Bf[kc], acc[m], 0, 0, 0);
        }
    }
    __syncthreads();

    // --- epilogue: stage 64px x 64oc f32 tile, coalesced NCHW store ---
    float* ot = reinterpret_cast<float*>(smem);          // [64][65]
    float bias = b_def[wave * 16 + (lane & 15)];
    #pragma unroll
    for (int m = 0; m < 4; ++m) {
        #pragma unroll
        for (int j = 0; j < 4; ++j) {
            int prow = m * 16 + ((lane >> 4) << 2) + j;   // pixel
            ot[prow * 65 + wave * 16 + (lane & 15)] = acc[m][j] + bias;
        }
    }
    __syncthreads();
    #pragma unroll
    for (int r = 0; r < 16; ++r) {
        int idx = r * 256 + tid;
        int oc = idx >> 6, pw = idx & 63;
        out[(((size_t)b * O_ + oc) * H_ + h) * W_ + w0 + pw] = ot[pw * 65 + oc];
    }
}

// ---------------------------------------------------------------------------
extern "C" void kernel_launch(void* const* d_in, const int* in_sizes, int n_in,
                              void* d_out, int out_size, void* d_ws, size_t ws_size,
                              hipStream_t stream) {
    const float* x     = (const float*)d_in[0];
    const float* w_off = (const float*)d_in[1];
    const float* b_off = (const float*)d_in[2];
    const float* w_def = (const float*)d_in[3];
    const float* b_def = (const float*)d_in[4];
    float* out = (float*)d_out;

    char* ws = (char*)d_ws;
    float* xT           = (float*)ws;                        // 33,554,432 B
    unsigned short* wTf = (unsigned short*)(ws + 33554432);  //     73,728 B
    unsigned short* wOf = (unsigned short*)(ws + 33554432 + 73728); // 36,864 B

    k_transpose<<<B_ * H_ * (W_ / 64), 256, 0, stream>>>(x, xT);
    k_wprep<<<(O_ * C_ * K2_ + 255) / 256, 256, 0, stream>>>(w_def, wTf);
    k_wprep_off<<<(36 * 512 + 255) / 256, 256, 0, stream>>>(w_off, wOf);
    k_fused<<<NPIX / 64, 256, 0, stream>>>(xT, wOf, b_off, wTf, b_def, out);
}